// Round 1
// baseline (131.820 us; speedup 1.0000x reference)
//
#include <hip/hip_runtime.h>

// SplineActivation: out[b,d] = sum_k basis_k(x[b,d]) * coeffs[d,k]
// Uniform knots (h=0.5 on [-2.5,2.5]) => closed-form uniform cubic B-spline:
// only 4 of 7 basis funcs nonzero; weights are cubic polynomials of the
// fractional cell coordinate. HBM-bound: 64MB in + 64MB out.

#define INPUT_DIM 4096
#define BATCH     4096
#define N_BASIS   7

constexpr int N_ELEM = BATCH * INPUT_DIM;
constexpr int N_VEC4 = N_ELEM / 4;

__global__ __launch_bounds__(256) void
spline_act_kernel(const float* __restrict__ x,
                  const float* __restrict__ coeffs,
                  float* __restrict__ out) {
    int t = blockIdx.x * blockDim.x + threadIdx.x;
    if (t >= N_VEC4) return;

    const float4* x4 = reinterpret_cast<const float4*>(x);
    float4*       o4 = reinterpret_cast<float4*>(out);

    float4 xv = x4[t];
    // d index of the first lane-element; D % 4 == 0 so no row wrap inside a float4
    int d0 = (t * 4) & (INPUT_DIM - 1);

    float xs[4] = {xv.x, xv.y, xv.z, xv.w};
    float r[4];

#pragma unroll
    for (int j = 0; j < 4; ++j) {
        // u in [0,4): cell coordinate on the 4 interior intervals of [-1,1]
        float u = (xs[j] + 1.0f) * 2.0f;
        int c = (int)floorf(u);
        c = c < 0 ? 0 : (c > 3 ? 3 : c);   // clamp (handles x==1.0 rounding)
        float s = u - (float)c;            // fractional position in cell, [0,1]

        float s2 = s * s;
        float s3 = s2 * s;
        float omt = 1.0f - s;
        const float k6 = 1.0f / 6.0f;
        float w0 = omt * omt * omt * k6;
        float w1 = (3.0f * s3 - 6.0f * s2 + 4.0f) * k6;
        float w2 = (-3.0f * s3 + 3.0f * s2 + 3.0f * s + 1.0f) * k6;
        float w3 = s3 * k6;

        const float* cp = coeffs + (d0 + j) * N_BASIS + c;
        r[j] = w0 * cp[0] + w1 * cp[1] + w2 * cp[2] + w3 * cp[3];
    }

    o4[t] = make_float4(r[0], r[1], r[2], r[3]);
}

extern "C" void kernel_launch(void* const* d_in, const int* in_sizes, int n_in,
                              void* d_out, int out_size, void* d_ws, size_t ws_size,
                              hipStream_t stream) {
    const float* x      = (const float*)d_in[0];   // (4096, 4096) fp32
    const float* coeffs = (const float*)d_in[1];   // (4096, 7) fp32
    float* out          = (float*)d_out;           // (4096, 4096) fp32

    const int block = 256;
    const int grid  = (N_VEC4 + block - 1) / block;  // 16384 blocks
    spline_act_kernel<<<grid, block, 0, stream>>>(x, coeffs, out);
}

// Round 2
// 115.623 us; speedup vs baseline: 1.1401x; 1.1401x over previous
//
#include <hip/hip_runtime.h>

// SplineActivation: out[b,d] = sum_k basis_k(x[b,d]) * coeffs[d,k]
// Uniform cubic B-spline closed form: 4 nonzero weights per element.
// Gather moved from global (line-divergent, TA-bound) into LDS.
// Block = 512-d tile x 16 rows; stages 14 KB coeffs once, then streams.

#define D       4096
#define B       4096
#define NB      7
#define DTILE   512
#define ROWS    16

constexpr int NDT   = D / DTILE;     // 8 d-tiles
constexpr int NRT   = B / ROWS;      // 256 row-tiles
constexpr int NCOEF = DTILE * NB;    // 3584 floats = 14 KB

__global__ __launch_bounds__(256, 8) void
spline_act_kernel(const float* __restrict__ x,
                  const float* __restrict__ coeffs,
                  float* __restrict__ out) {
    __shared__ float sc[NCOEF];

    const int bid   = blockIdx.x;
    const int dt    = bid & (NDT - 1);     // d-tile index (fast-varying for L2 reuse)
    const int rowt  = bid >> 3;            // row-tile index
    const int dbase = dt * DTILE;

    // Stage this tile's coeffs into LDS (coalesced: 3584 floats / 256 thr = 14 each)
    for (int i = threadIdx.x; i < NCOEF; i += 256)
        sc[i] = coeffs[dbase * NB + i];
    __syncthreads();

    const int tid  = threadIdx.x;
    const int pos  = tid & 127;            // float4 position within the 512-d segment
    const int rsub = tid >> 7;             // 0 or 1: which of 2 rows this iteration
    const int dl0  = pos * 4;              // local d of this thread's first element

    const float4* x4 = reinterpret_cast<const float4*>(x);
    float4*       o4 = reinterpret_cast<float4*>(out);

    const int rowbase = rowt * ROWS;
    const float k6 = 1.0f / 6.0f;

#pragma unroll 2
    for (int it = 0; it < ROWS / 2; ++it) {
        int row = rowbase + it * 2 + rsub;
        int idx = row * (D / 4) + (dbase >> 2) + pos;   // float4 index

        float4 xv = x4[idx];
        float xs[4] = {xv.x, xv.y, xv.z, xv.w};
        float r[4];

#pragma unroll
        for (int j = 0; j < 4; ++j) {
            float u = (xs[j] + 1.0f) * 2.0f;     // cell coord in [0,4)
            int c = (int)floorf(u);
            c = c < 0 ? 0 : (c > 3 ? 3 : c);
            float s = u - (float)c;

            float s2  = s * s;
            float s3  = s2 * s;
            float omt = 1.0f - s;
            float w0 = omt * omt * omt * k6;
            float w1 = (3.0f * s3 - 6.0f * s2 + 4.0f) * k6;
            float w2 = (-3.0f * s3 + 3.0f * s2 + 3.0f * s + 1.0f) * k6;
            float w3 = s3 * k6;

            const float* cp = &sc[(dl0 + j) * NB + c];
            r[j] = w0 * cp[0] + w1 * cp[1] + w2 * cp[2] + w3 * cp[3];
        }

        o4[idx] = make_float4(r[0], r[1], r[2], r[3]);
    }
}

extern "C" void kernel_launch(void* const* d_in, const int* in_sizes, int n_in,
                              void* d_out, int out_size, void* d_ws, size_t ws_size,
                              hipStream_t stream) {
    const float* x      = (const float*)d_in[0];   // (4096, 4096) fp32
    const float* coeffs = (const float*)d_in[1];   // (4096, 7) fp32
    float* out          = (float*)d_out;           // (4096, 4096) fp32

    const int grid = NDT * NRT;   // 2048 blocks, 256 threads each
    spline_act_kernel<<<grid, 256, 0, stream>>>(x, coeffs, out);
}

// Round 3
// 113.763 us; speedup vs baseline: 1.1587x; 1.0163x over previous
//
#include <hip/hip_runtime.h>

// SplineActivation: out[b,d] = sum_k basis_k(x[b,d]) * coeffs[d,k]
// Uniform cubic B-spline closed form: 4 nonzero taps per element.
// LDS holds, per d, the 4 possible 4-tap windows pre-packed as float4
// (stride 80 B per d -> gather is ONE ds_read_b128, banks near-even).

#define D     4096
#define B     4096
#define NB    7
#define DTILE 256
#define ROWS  16

constexpr int NDT    = D / DTILE;   // 16 d-tiles
constexpr int NRT    = B / ROWS;    // 256 row-tiles
constexpr int STRIDE = 20;          // words per d: 4 packs * 4 words + 4 pad

__global__ __launch_bounds__(256, 8) void
spline_act_kernel(const float* __restrict__ x,
                  const float* __restrict__ coeffs,
                  float* __restrict__ out) {
    __shared__ float sc[DTILE * STRIDE];   // 20 KB

    const int bid   = blockIdx.x;
    const int dt    = bid & (NDT - 1);
    const int rowt  = bid >> 4;
    const int dbase = dt * DTILE;

    // Stage + pack: thread i owns local d = i. Writes 4 aligned float4 windows.
    {
        const int i = threadIdx.x;
        const float* crow = coeffs + (size_t)(dbase + i) * NB;
        float c0 = crow[0], c1 = crow[1], c2 = crow[2], c3 = crow[3];
        float c4 = crow[4], c5 = crow[5], c6 = crow[6];
        float* bp = &sc[i * STRIDE];
        *reinterpret_cast<float4*>(bp + 0)  = make_float4(c0, c1, c2, c3);
        *reinterpret_cast<float4*>(bp + 4)  = make_float4(c1, c2, c3, c4);
        *reinterpret_cast<float4*>(bp + 8)  = make_float4(c2, c3, c4, c5);
        *reinterpret_cast<float4*>(bp + 12) = make_float4(c3, c4, c5, c6);
    }
    __syncthreads();

    const int tid  = threadIdx.x;
    const int pos  = tid & 63;     // float4 position within 256-d segment (= lane)
    const int rsub = tid >> 6;     // which of 4 concurrent rows

    const float4* x4 = reinterpret_cast<const float4*>(x);
    float4*       o4 = reinterpret_cast<float4*>(out);

    const int rowbase = rowt * ROWS;
    const float k6 = 1.0f / 6.0f;

#pragma unroll
    for (int it = 0; it < ROWS / 4; ++it) {
        int row = rowbase + it * 4 + rsub;
        int idx = row * (D / 4) + (dbase >> 2) + pos;

        float4 xv = x4[idx];
        float xs[4] = {xv.x, xv.y, xv.z, xv.w};
        float r[4];

#pragma unroll
        for (int j = 0; j < 4; ++j) {
            float u = (xs[j] + 1.0f) * 2.0f;     // cell coord in [0,4)
            int c = (int)floorf(u);
            c = c < 0 ? 0 : (c > 3 ? 3 : c);
            float s = u - (float)c;

            float s2  = s * s;
            float s3  = s2 * s;
            float omt = 1.0f - s;
            float w0 = omt * omt * omt * k6;
            float w1 = (3.0f * s3 - 6.0f * s2 + 4.0f) * k6;
            float w2 = (-3.0f * s3 + 3.0f * s2 + 3.0f * s + 1.0f) * k6;
            float w3 = s3 * k6;

            int dl = 4 * pos + j;
            float4 cv = *reinterpret_cast<const float4*>(&sc[dl * STRIDE + 4 * c]);
            r[j] = w0 * cv.x + w1 * cv.y + w2 * cv.z + w3 * cv.w;
        }

        o4[idx] = make_float4(r[0], r[1], r[2], r[3]);
    }
}

extern "C" void kernel_launch(void* const* d_in, const int* in_sizes, int n_in,
                              void* d_out, int out_size, void* d_ws, size_t ws_size,
                              hipStream_t stream) {
    const float* x      = (const float*)d_in[0];   // (4096, 4096) fp32
    const float* coeffs = (const float*)d_in[1];   // (4096, 7) fp32
    float* out          = (float*)d_out;           // (4096, 4096) fp32

    const int grid = NDT * NRT;   // 4096 blocks x 256 threads
    spline_act_kernel<<<grid, 256, 0, stream>>>(x, coeffs, out);
}